// Round 3
// baseline (243.090 us; speedup 1.0000x reference)
//
#include <hip/hip_runtime.h>

// Layout (established rounds 0-4 of prior session):
//   d_in[0] tokens : int32, R=256 x L=512
//   d_in[1] lprobs : fp32,  R=256 x V=128000 (131 MB)
//   d_in[2] bsz, d_in[3] beam_size, d_in[4] step : 1-elem int arrays
//   d_out  : fp32, same shape as lprobs
//
// Correctness model (hard-won, do not regress):
//   * Harness compares through bfloat16. fp32 -FLT_MAX rounds UP to bf16
//     -inf -> (-inf)-(-inf)=nan -> fail. Sentinel 0xFF7F0000 = most
//     negative finite bf16: finite in fp32 AND after bf16 rounding.
//   * Every byte of d_out written deterministically each call.
//
// Timing model (round 2 post-mortem):
//   * ~165 us of the 230-235 us timed window is harness re-poison
//     (524 MB fill @ 6.4 TB/s + restore memsets). Controllable part is
//     only our kernel (<80 us; floor 42 us = 262 MB @ 6.3 TB/s).
//   * Non-temporal hints REGRESSED vs plain float4 (235.1 vs 230.9):
//     m13's 6.29 TB/s copy ceiling is plain float4. Do not reintroduce.
//
// Round 7 structure: single fused kernel, chunk-ownership (race-free):
//   block owns one 64 KB chunk of one row; hoists its token-window loads
//   (L2-hot, hidden under copy), copies chunk with plain float4 (unroll 4),
//   __syncthreads() (drains vmcnt -> copy stores committed), then writes
//   sentinel only for banned ids inside ITS chunk.

#define SENTINEL_BITS 0xFF7F0000u
#define CHUNK_ELEMS   16384        // fp32 elems per block-chunk (64 KB)
#define NGRAM_N       3
#define THREADS       256

typedef float f32x4 __attribute__((ext_vector_type(4)));

__global__ __launch_bounds__(THREADS)
void ngram_fused_kernel(const int* __restrict__ tokens,
                        const float* __restrict__ lprobs,
                        float* __restrict__ out,
                        const int* __restrict__ step_ptr,
                        int tokens_count, int lprobs_count)
{
    const int step = *step_ptr;
    const int L = step + 1;
    const int R = (L > 0) ? (tokens_count / L) : 0;
    const int V = (R > 0) ? (lprobs_count / R) : 0;

    if (R <= 0 || V <= 0) {
        // Degenerate shape: deterministic flat copy, no bans.
        long nTot = lprobs_count;
        long stride = (long)gridDim.x * blockDim.x;
        for (long k = (long)blockIdx.x * blockDim.x + threadIdx.x;
             k < nTot; k += stride)
            out[k] = lprobs[k];
        return;
    }

    const bool do_ban  = (step + 2 - NGRAM_N) >= 0;   // reference early-out
    const int  W       = L - NGRAM_N + 1;             // window count
    const int  p_start = step + 2 - NGRAM_N;          // prefix start
    const float sentinel = __uint_as_float(SENTINEL_BITS);
    const bool vec_ok = ((V & 3) == 0);               // chunk bounds /4-exact

    const int  chunks_per_row = (V + CHUNK_ELEMS - 1) / CHUNK_ELEMS;
    const long total_chunks   = (long)R * chunks_per_row;
    const int  tid = (int)threadIdx.x;

    for (long c = blockIdx.x; c < total_chunks; c += gridDim.x) {
        const int r  = (int)(c / chunks_per_row);
        const int ci = (int)(c % chunks_per_row);
        const int e0 = ci * CHUNK_ELEMS;
        const int e1 = min(e0 + CHUNK_ELEMS, V);
        const size_t rbase = (size_t)r * V;

        // ---- phase 0: issue this thread's token-window loads EARLY ----
        // (L2-hot 2 KB/row; latency hides under the 64 KB chunk copy)
        const int* trow = tokens + (size_t)r * L;
        int p0 = 0, p1 = 0;
        int w0 = -1, w1 = -1;          // up to 2 windows/thread (W<=510)
        int t00 = 0, t01 = 0, t02 = 0;
        int t10 = 0, t11 = 0, t12 = 0;
        if (do_ban && W > 0) {
            p0 = trow[p_start];
            p1 = trow[p_start + 1];
            int w = tid;
            if (w < W) { w0 = w; t00 = trow[w]; t01 = trow[w+1]; t02 = trow[w+2]; }
            w += THREADS;
            if (w < W) { w1 = w; t10 = trow[w]; t11 = trow[w+1]; t12 = trow[w+2]; }
            // Shape guard: if W > 2*THREADS, fall through to strided loop below.
        }

        // ---- phase 1: copy this chunk, plain float4 (m13 pattern) ----
        if (vec_ok) {
            const f32x4* in4  = (const f32x4*)(lprobs + rbase);
            f32x4*       out4 = (f32x4*)(out + rbase);
            const int f0 = e0 >> 2;
            const int f1 = e1 >> 2;
            #pragma unroll 4
            for (int k = f0 + tid; k < f1; k += THREADS) {
                out4[k] = in4[k];
            }
        } else {
            for (int e = e0 + tid; e < e1; e += THREADS)
                out[rbase + e] = lprobs[rbase + e];
        }

        // ---- phase 2: ban overwrites restricted to this chunk ----
        if (do_ban && W > 0) {
            // Uniform across block: barrier safe. Implicit vmcnt(0) drain
            // commits phase-1 stores before sentinel overwrites.
            __syncthreads();
            if (w0 >= 0 && t00 == p0 && t01 == p1 && t02 >= e0 && t02 < e1)
                out[rbase + t02] = sentinel;            // idempotent
            if (w1 >= 0 && t10 == p0 && t11 == p1 && t12 >= e0 && t12 < e1)
                out[rbase + t12] = sentinel;
            // Safety for shapes with W > 2*THREADS (not hit at L=512):
            for (int w = tid + 2 * THREADS; w < W; w += THREADS) {
                if (trow[w] == p0 && trow[w + 1] == p1) {
                    const int banned = trow[w + 2];
                    if (banned >= e0 && banned < e1)
                        out[rbase + banned] = sentinel;
                }
            }
        }
    }
}

extern "C" void kernel_launch(void* const* d_in, const int* in_sizes, int n_in,
                              void* d_out, int out_size, void* d_ws, size_t ws_size,
                              hipStream_t stream) {
    const int*   tokens   = (const int*)d_in[0];
    const float* lprobs   = (const float*)d_in[1];
    const int*   step_ptr = (const int*)d_in[4];   // bsz/beam unused (derived)
    float*       out      = (float*)d_out;

    // One 64 KB chunk per block: 2048 blocks at the bench shape
    // (256 rows x ceil(128000/16384)=8 chunks) = 8 blocks/CU, 32 waves/CU.
    const int threads = THREADS;
    long est_chunks = ((long)out_size + CHUNK_ELEMS - 1) / CHUNK_ELEMS + 256;
    int blocks = (est_chunks < 2048) ? (int)est_chunks : 2048;
    if (blocks < 1) blocks = 1;

    ngram_fused_kernel<<<blocks, threads, 0, stream>>>(
        tokens, lprobs, out, step_ptr, in_sizes[0], in_sizes[1]);
}

// Round 4
// 241.347 us; speedup vs baseline: 1.0072x; 1.0072x over previous
//
#include <hip/hip_runtime.h>

// Layout (established rounds 0-4 of prior session):
//   d_in[0] tokens : int32, R=256 x L=512
//   d_in[1] lprobs : fp32,  R=256 x V=128000 (131 MB)
//   d_in[2] bsz, d_in[3] beam_size, d_in[4] step : 1-elem int arrays
//   d_out  : fp32, same shape as lprobs
//
// Correctness model (hard-won, do not regress):
//   * Harness compares through bfloat16. fp32 -FLT_MAX rounds UP to bf16
//     -inf -> (-inf)-(-inf)=nan -> fail. Sentinel 0xFF7F0000 = most
//     negative finite bf16: finite in fp32 AND after bf16 rounding.
//   * Every byte of d_out written deterministically each call.
//
// Timing model (rounds 2-3 post-mortem):
//   * Timed window ~230-243 us = harness re-poison fills (~80 us each,
//     6.5 TB/s) + restores + our kernel. Controllable part = our kernel.
//   * Our kernel measured 80.6 us @ 2.47 TB/s HBM (31% peak), VALUBusy
//     2.2%, Occ 51% -> latency-bound copy, NOT bandwidth-bound.
//     Fill proves 6.5 TB/s is available. Fusion itself was neutral.
//   * Non-temporal hints regressed (do not reintroduce). Token-load
//     hoisting regressed/neutral (dropped).
//
// Round 8 structure: fused kernel, chunk-ownership (race-free), with
//   DEEP-BATCHED copy: 8 back-to-back dwordx4 loads then 8 stores per
//   round (8 outstanding loads/wave vs ~4 before), 2 rounds per 64 KB
//   chunk. 32 data VGPRs -> still 8 blocks/CU. Ban pass: simple strided
//   loop after __syncthreads (vmcnt drain orders copy stores first).

#define SENTINEL_BITS 0xFF7F0000u
#define CHUNK_ELEMS   16384        // fp32 elems per block-chunk (64 KB)
#define NGRAM_N       3
#define THREADS       256
#define BATCH         8            // dwordx4 loads in flight per thread

typedef float f32x4 __attribute__((ext_vector_type(4)));

__global__ __launch_bounds__(THREADS)
void ngram_fused_kernel(const int* __restrict__ tokens,
                        const float* __restrict__ lprobs,
                        float* __restrict__ out,
                        const int* __restrict__ step_ptr,
                        int tokens_count, int lprobs_count)
{
    const int step = *step_ptr;
    const int L = step + 1;
    const int R = (L > 0) ? (tokens_count / L) : 0;
    const int V = (R > 0) ? (lprobs_count / R) : 0;

    if (R <= 0 || V <= 0) {
        // Degenerate shape: deterministic flat copy, no bans.
        long nTot = lprobs_count;
        long stride = (long)gridDim.x * blockDim.x;
        for (long k = (long)blockIdx.x * blockDim.x + threadIdx.x;
             k < nTot; k += stride)
            out[k] = lprobs[k];
        return;
    }

    const bool do_ban  = (step + 2 - NGRAM_N) >= 0;   // reference early-out
    const int  W       = L - NGRAM_N + 1;             // window count
    const int  p_start = step + 2 - NGRAM_N;          // prefix start
    const float sentinel = __uint_as_float(SENTINEL_BITS);
    const bool vec_ok = ((V & 3) == 0);               // chunk bounds /4-exact

    const int  chunks_per_row = (V + CHUNK_ELEMS - 1) / CHUNK_ELEMS;
    const long total_chunks   = (long)R * chunks_per_row;
    const int  tid = (int)threadIdx.x;

    for (long c = blockIdx.x; c < total_chunks; c += gridDim.x) {
        const int r  = (int)(c / chunks_per_row);
        const int ci = (int)(c % chunks_per_row);
        const int e0 = ci * CHUNK_ELEMS;
        const int e1 = min(e0 + CHUNK_ELEMS, V);
        const size_t rbase = (size_t)r * V;

        // ---- phase 1: deep-batched float4 copy of this chunk ----
        if (vec_ok) {
            const f32x4* __restrict__ in4  = (const f32x4*)(lprobs + rbase);
            f32x4* __restrict__       out4 = (f32x4*)(out + rbase);
            const int f0 = e0 >> 2;
            const int f1 = e1 >> 2;          // bench shape: f1-f0 = 4096
            int k = f0 + tid;
            // main: BATCH loads issued back-to-back, then BATCH stores.
            // All indices compile-time static (no scratch - rule #20).
            for (; k + (BATCH - 1) * THREADS < f1; k += BATCH * THREADS) {
                f32x4 v[BATCH];
                #pragma unroll
                for (int b = 0; b < BATCH; ++b) v[b] = in4[k + b * THREADS];
                #pragma unroll
                for (int b = 0; b < BATCH; ++b) out4[k + b * THREADS] = v[b];
            }
            // remainder float4 (none at bench shape)
            for (; k < f1; k += THREADS) out4[k] = in4[k];
        } else {
            for (int e = e0 + tid; e < e1; e += THREADS)
                out[rbase + e] = lprobs[rbase + e];
        }

        // ---- phase 2: ban overwrites restricted to this chunk ----
        if (do_ban && W > 0) {
            // Uniform condition across block: barrier safe. Implicit
            // vmcnt(0) drain commits phase-1 stores before overwrites.
            __syncthreads();
            const int* trow = tokens + (size_t)r * L;    // 2 KB, L2-hot
            const int p0 = trow[p_start];
            const int p1 = trow[p_start + 1];
            for (int w = tid; w < W; w += THREADS) {
                if (trow[w] == p0 && trow[w + 1] == p1) {
                    const int banned = trow[w + 2];
                    if (banned >= e0 && banned < e1)
                        out[rbase + banned] = sentinel;   // idempotent
                }
            }
        }
    }
}

extern "C" void kernel_launch(void* const* d_in, const int* in_sizes, int n_in,
                              void* d_out, int out_size, void* d_ws, size_t ws_size,
                              hipStream_t stream) {
    const int*   tokens   = (const int*)d_in[0];
    const float* lprobs   = (const float*)d_in[1];
    const int*   step_ptr = (const int*)d_in[4];   // bsz/beam unused (derived)
    float*       out      = (float*)d_out;

    // One 64 KB chunk per block: 2048 blocks at the bench shape
    // (256 rows x 8 chunks) = 8 blocks/CU, 32 waves/CU.
    const int threads = THREADS;
    long est_chunks = ((long)out_size + CHUNK_ELEMS - 1) / CHUNK_ELEMS + 256;
    int blocks = (est_chunks < 2048) ? (int)est_chunks : 2048;
    if (blocks < 1) blocks = 1;

    ngram_fused_kernel<<<blocks, threads, 0, stream>>>(
        tokens, lprobs, out, step_ptr, in_sizes[0], in_sizes[1]);
}